// Round 9
// baseline (9872.265 us; speedup 1.0000x reference)
//
#include <hip/hip_runtime.h>
#include <cstdint>
#include <cstddef>

// Problem constants
#define B   16
#define SEQ 512
#define HD  768
#define G4  3072   // 4*HD
#define NL  25
#define NBLK 96    // blocks per direction in the scan (8 h-units each)

using u16 = unsigned short;
using u32 = uint32_t;
using u64 = unsigned long long;

#define XGD ((size_t)96*SEQ*512)   // u16 elements per dir in repacked xg

__device__ __forceinline__ float bf2f(u16 u){
  union { float f; u32 i; } v; v.i = ((u32)u) << 16; return v.f;
}
__device__ __forceinline__ u16 f2bf(float f){
  union { float f; u32 i; } v; v.f = f;
  u32 r = v.i + 0x7FFFu + ((v.i >> 16) & 1u);  // RNE
  return (u16)(r >> 16);
}
__device__ __forceinline__ float asf(u32 u){ union { float f; u32 i; } v; v.i = u; return v.f; }
__device__ __forceinline__ float sigm(float x){ return 1.f/(1.f + __expf(-x)); }
__device__ __forceinline__ float tanhfast(float x){ return 1.f - 2.f/(__expf(2.f*x) + 1.f); }

typedef __attribute__((ext_vector_type(8))) short bf16x8;
typedef __attribute__((ext_vector_type(4))) float f32x4;

// stage 8 bf16 (16B) into LDS from either bf16 or fp32 global source
__device__ __forceinline__ void stage_to_lds(u16* dst, const u16* src){
  *(uint4*)dst = *(const uint4*)src;
}
__device__ __forceinline__ void stage_to_lds(u16* dst, const float* src){
  float4 a = *(const float4*)src;
  float4 b = *(const float4*)(src + 4);
  uint4 v;
  v.x = (u32)f2bf(a.x) | ((u32)f2bf(a.y) << 16);
  v.y = (u32)f2bf(a.z) | ((u32)f2bf(a.w) << 16);
  v.z = (u32)f2bf(b.x) | ((u32)f2bf(b.y) << 16);
  v.w = (u32)f2bf(b.z) | ((u32)f2bf(b.w) << 16);
  *(uint4*)dst = v;
}

// ---------------------------------------------------------------------------
// prep: bias[lid][g] = b_ih + b_hh
// ---------------------------------------------------------------------------
struct BPtrs { const float* bi[4]; const float* bh[4]; };

__global__ void prep_bias(BPtrs p, float* __restrict__ bias){
  int idx = blockIdx.x*blockDim.x + threadIdx.x;
  if (idx < 4*G4){
    int lid = idx / G4, g = idx % G4;
    bias[idx] = p.bi[lid][g] + p.bh[lid][g];
  }
}

// ---------------------------------------------------------------------------
// MFMA xg GEMM, writes xg REPACKED for the scan: dst[js8][t][g][b][jl8]
// (unchanged from rounds 6-8, verified)
// ---------------------------------------------------------------------------
template<typename AT>
__global__ __launch_bounds__(256) void gemm_xg_mfma(const AT* __restrict__ A, int K,
    const float* __restrict__ W, const float* __restrict__ bias, u16* __restrict__ out)
{
  __shared__ u16 As[128][40];
  __shared__ u16 Bs[128][40];
  const int tid = threadIdx.x;
  const int bm = blockIdx.y * 128;
  const int bn = blockIdx.x * 128;
  const int wid = tid >> 6, lane = tid & 63;
  const int wr = wid >> 1, wc = wid & 1;
  const int kq = lane >> 4, rl = lane & 15;

  f32x4 acc[4][4];
  #pragma unroll
  for (int mf = 0; mf < 4; mf++)
    #pragma unroll
    for (int nf = 0; nf < 4; nf++) acc[mf][nf] = (f32x4){0.f,0.f,0.f,0.f};

  for (int k0 = 0; k0 < K; k0 += 32){
    #pragma unroll
    for (int u = 0; u < 2; u++){
      int c = tid + u*256;
      int r = c >> 2, q = c & 3;
      stage_to_lds(&As[r][q*8], A + (size_t)(bm + r)*K + k0 + q*8);
      stage_to_lds(&Bs[r][q*8], W + (size_t)(bn + r)*K + k0 + q*8);
    }
    __syncthreads();
    bf16x8 af[4], bfr[4];
    #pragma unroll
    for (int mf = 0; mf < 4; mf++) af[mf]  = *(const bf16x8*)&As[wr*64 + mf*16 + rl][kq*8];
    #pragma unroll
    for (int nf = 0; nf < 4; nf++) bfr[nf] = *(const bf16x8*)&Bs[wc*64 + nf*16 + rl][kq*8];
    #pragma unroll
    for (int mf = 0; mf < 4; mf++)
      #pragma unroll
      for (int nf = 0; nf < 4; nf++)
        acc[mf][nf] = __builtin_amdgcn_mfma_f32_16x16x32_bf16(af[mf], bfr[nf], acc[mf][nf], 0, 0, 0);
    __syncthreads();
  }

  float bv[4];
  size_t coloff[4];
  #pragma unroll
  for (int nf = 0; nf < 4; nf++){
    int n = bn + wc*64 + nf*16 + rl;
    bv[nf] = bias[n];
    int g = n / 768, j = n - g*768;
    coloff[nf] = (size_t)(j >> 3)*262144 + (size_t)g*128 + (j & 7);
  }
  #pragma unroll
  for (int mf = 0; mf < 4; mf++){
    #pragma unroll
    for (int i = 0; i < 4; i++){
      int row = bm + wr*64 + mf*16 + kq*4 + i;     // = b*SEQ + t
      int b = row >> 9, t = row & 511;
      size_t rowoff = (size_t)t*512 + (size_t)b*8;
      #pragma unroll
      for (int nf = 0; nf < 4; nf++)
        out[coloff[nf] + rowoff] = f2bf(acc[mf][nf][i] + bv[nf]);
    }
  }
}

// ---------------------------------------------------------------------------
// Persistent LSTM scan — TAG-EMBEDDED exchange (no flags, no drains).
// R5 geometry: 192 blocks x 256 thr (4 waves); dir = bid/96, js = bid%96
// (8 h-units). Waves split K=768 into 4x192.
//
// h exchange: hgt[u64] = { tag (hi32) , bf16 pair k=2p,2p+1 (lo32) }.
// Layout [2 ping][2 dir][16 b][384 p]. h(s) carries tag==s; memset 0 gives
// h(0)=0 with tag 0. Producer of step s+1 stores tag s+1 into slot (s+1)&1.
//
// Safety (ping-pong depth 2): consuming step s requires EVERY producer's
// tag-s u64 observed, so "X published s+1" implies all blocks published s,
// which implies all blocks' reads of step s-1 retired => overwriting
// slot (s+1)&1 (holding step s-1) is safe. A consumer of step s can never
// observe tag s+2: that write requires all blocks consumed s+1 > s first.
//
// Per step: xg prefetch -> 24 u64 loads (parallel; stale-retry loop) ->
// 12 MFMA -> red[s&1] write -> __syncthreads (the only barrier) ->
// tid<128: gates -> publish tagged u64 pairs -> hout (off critical path).
// ---------------------------------------------------------------------------
template<int LAYER>
__global__ __launch_bounds__(256, 1) void scan_kernel(
    const u16* __restrict__ xgp,     // [dir][js8][t][g][b][jl8]
    const float* __restrict__ whh_f, // [3072][768]
    const float* __restrict__ whh_r,
    u64* __restrict__ hgt,           // [2][2][16][384] tagged bf16 pairs
    u16* __restrict__ hout)          // [b*SEQ+t][1536]
{
  __shared__ float red[2][32*16*4];  // ping-pong [j_local][b][wave]
  __shared__ float cL[128];          // c state [jh_l][b]

  const int tid  = threadIdx.x;
  const int dir  = blockIdx.x / NBLK;
  const int js   = blockIdx.x % NBLK;
  const int w    = tid >> 6;
  const int lane = tid & 63;
  const int lr   = lane & 15;   // A-row / B-col (b)
  const int lq   = lane >> 4;   // k-octet selector

  const float* Wsrc = dir ? whh_r : whh_f;

  // one-time A-frag preload: af[m][c] covers j = m*16+lr, k = w*192+c*32+lq*8
  bf16x8 af[2][6];
  #pragma unroll
  for (int m = 0; m < 2; m++){
    int j_local = m*16 + lr;
    int j_glob  = (j_local >> 3)*768 + js*8 + (j_local & 7);  // gate-major rows
    const float* rowp = Wsrc + (size_t)j_glob*HD;
    #pragma unroll
    for (int c = 0; c < 6; c++){
      int k = w*192 + c*32 + lq*8;
      float4 a  = *(const float4*)(rowp + k);
      float4 b4 = *(const float4*)(rowp + k + 4);
      union { u32 u[4]; bf16x8 v; } t;
      t.u[0] = (u32)f2bf(a.x)  | ((u32)f2bf(a.y)  << 16);
      t.u[1] = (u32)f2bf(a.z)  | ((u32)f2bf(a.w)  << 16);
      t.u[2] = (u32)f2bf(b4.x) | ((u32)f2bf(b4.y) << 16);
      t.u[3] = (u32)f2bf(b4.z) | ((u32)f2bf(b4.w) << 16);
      af[m][c] = t.v;
    }
  }
  if (tid < 128) cL[tid] = 0.f;
  __syncthreads();

  const int jh_l = tid >> 4;    // 0..7 (valid for tid<128)
  const int b_g  = tid & 15;

  for (int s = 0; s < SEQ; s++){
    const int t_seq = dir ? (SEQ-1-s) : s;
    const u32 want = (u32)s;

    // xg prefetch (contiguous 1KB/block-step region)
    float xgv[4];
    if (tid < 128){
      const u16* xp = xgp + (size_t)dir*XGD + (size_t)js*262144
                    + (size_t)t_seq*512 + b_g*8 + jh_l;
      #pragma unroll
      for (int g = 0; g < 4; g++) xgv[g] = bf2f(xp[g*128]);
    }

    // tagged h loads: pair index p = w*96 + c*16 + lq*4 + i, row b = lr
    const u64* hb = hgt + (size_t)((s&1)*2 + dir)*6144 + lr*384 + w*96;
    u64 q[6][4];
    #pragma unroll
    for (int c = 0; c < 6; c++)
      #pragma unroll
      for (int i = 0; i < 4; i++)
        q[c][i] = __hip_atomic_load(hb + c*16 + lq*4 + i,
                                    __ATOMIC_RELAXED, __HIP_MEMORY_SCOPE_AGENT);
    // retry stale entries until every tag == s (bitwise check forces all
    // 24 loads issued in parallel before the first wait)
    while (true){
      u32 stale = 0;
      #pragma unroll
      for (int c = 0; c < 6; c++)
        #pragma unroll
        for (int i = 0; i < 4; i++)
          stale |= ((u32)(q[c][i] >> 32) != want) ? (1u << (c*4 + i)) : 0u;
      if (!stale) break;
      #pragma unroll
      for (int c = 0; c < 6; c++)
        #pragma unroll
        for (int i = 0; i < 4; i++)
          if (stale & (1u << (c*4 + i)))
            q[c][i] = __hip_atomic_load(hb + c*16 + lq*4 + i,
                                        __ATOMIC_RELAXED, __HIP_MEMORY_SCOPE_AGENT);
    }

    f32x4 acc0 = (f32x4){0.f,0.f,0.f,0.f};
    f32x4 acc1 = (f32x4){0.f,0.f,0.f,0.f};
    #pragma unroll
    for (int c = 0; c < 6; c++){
      union { u32 u[4]; bf16x8 v; } bu;
      #pragma unroll
      for (int i = 0; i < 4; i++) bu.u[i] = (u32)q[c][i];
      acc0 = __builtin_amdgcn_mfma_f32_16x16x32_bf16(af[0][c], bu.v, acc0, 0, 0, 0);
      acc1 = __builtin_amdgcn_mfma_f32_16x16x32_bf16(af[1][c], bu.v, acc1, 0, 0, 0);
    }

    // cross-wave K reduce via LDS (ping-pong; safe with single barrier:
    // step s+1 writes red[(s+1)&1], and red[s&1] is reused only at s+2,
    // after waves 0/1 passed barrier(s+1), i.e. after gates(s) read it)
    float* rb = red[s & 1];
    #pragma unroll
    for (int i = 0; i < 4; i++){
      rb[(( 0 + lq*4 + i)*16 + lr)*4 + w] = acc0[i];
      rb[((16 + lq*4 + i)*16 + lr)*4 + w] = acc1[i];
    }
    __syncthreads();   // the ONE barrier per step

    if (tid < 128){
      float gs[4];
      #pragma unroll
      for (int g = 0; g < 4; g++){
        const float4 r4 = *(const float4*)&rb[((g*8 + jh_l)*16 + b_g)*4];
        gs[g] = r4.x + r4.y + r4.z + r4.w + xgv[g];
      }
      float c  = cL[tid];
      float ct = sigm(gs[1])*c + sigm(gs[0])*tanhfast(gs[2]);
      float h  = sigm(gs[3])*tanhfast(ct);
      cL[tid] = ct;

      const bool more = (s + 1 < SEQ);
      // pack (k even, k odd) pairs via shfl: partner tid^16 = jh_l^1, same b
      u32 hb16 = (u32)f2bf(h);
      u32 hoth = (u32)__shfl_xor((int)hb16, 16);
      float hw = (LAYER == 0) ? h : tanhfast(h);
      u32 ob16 = (u32)f2bf(hw);
      u32 ooth = (u32)__shfl_xor((int)ob16, 16);

      if (more && (jh_l & 1) == 0){
        u32 pair = (hb16 & 0xffffu) | (hoth << 16);
        u64 tagged = ((u64)(u32)(s + 1) << 32) | (u64)pair;
        u64* hdst = hgt + (size_t)(((s+1)&1)*2 + dir)*6144
                  + b_g*384 + js*4 + (jh_l >> 1);
        __hip_atomic_store(hdst, tagged, __ATOMIC_RELAXED, __HIP_MEMORY_SCOPE_AGENT);
      }
      // hout (h1 / tanh(h2)) off the critical path
      if ((jh_l & 1) == 0){
        u32 opair = (ob16 & 0xffffu) | (ooth << 16);
        u16* od = hout + ((size_t)b_g*SEQ + t_seq)*1536 + dir*HD + js*8 + jh_l;
        *(u32*)od = opair;
      }
    }
  }
}

// ---------------------------------------------------------------------------
// logits[row][l] = tanh(h2)[row] . clf_w[l] + clf_b[l]  (th already tanh'd)
// ---------------------------------------------------------------------------
__global__ __launch_bounds__(256) void logits_kernel(const u16* __restrict__ th,
    const float* __restrict__ clf_w, const float* __restrict__ clf_b,
    float* __restrict__ logits)
{
  __shared__ u16 xl[8*1536];
  const int tid = threadIdx.x;
  const int row0 = blockIdx.x * 8;
  {
    const uint4* src = (const uint4*)(th + (size_t)row0*1536);
    uint4* dst = (uint4*)xl;
    #pragma unroll
    for (int i = 0; i < 6; i++) dst[i*256 + tid] = src[i*256 + tid];
  }
  __syncthreads();
  const int r = tid >> 5, l = tid & 31;
  if (l < NL){
    float acc = clf_b[l];
    const float* wr = clf_w + (size_t)l*1536;
    #pragma unroll 2
    for (int kk = 0; kk < 192; kk++){
      uint4 xv = *(const uint4*)&xl[r*1536 + kk*8];
      float4 w0 = *(const float4*)(wr + kk*8);
      float4 w1 = *(const float4*)(wr + kk*8 + 4);
      acc = fmaf(asf(xv.x<<16), w0.x, acc); acc = fmaf(asf(xv.x&0xffff0000u), w0.y, acc);
      acc = fmaf(asf(xv.y<<16), w0.z, acc); acc = fmaf(asf(xv.y&0xffff0000u), w0.w, acc);
      acc = fmaf(asf(xv.z<<16), w1.x, acc); acc = fmaf(asf(xv.z&0xffff0000u), w1.y, acc);
      acc = fmaf(asf(xv.w<<16), w1.z, acc); acc = fmaf(asf(xv.w&0xffff0000u), w1.w, acc);
    }
    logits[(size_t)(row0 + r)*NL + l] = acc;
  }
}

// ---------------------------------------------------------------------------
// CRF numerator + lengths (per b)
// ---------------------------------------------------------------------------
__global__ __launch_bounds__(256) void crf_num(const float* __restrict__ logits,
    const int* __restrict__ targets, const float* __restrict__ trans,
    const float* __restrict__ start, const float* __restrict__ endv,
    float* __restrict__ numlen)
{
  const int b = blockIdx.x;
  const int* tg = targets + (size_t)b*SEQ;
  float s = 0.f; int cnt = 0;
  for (int t = threadIdx.x; t < SEQ; t += 256){
    int cur = tg[t];
    if (cur >= 0){
      cnt++;
      float e = logits[((size_t)b*SEQ + t)*NL + cur];
      s += e;
      if (t > 0) s += trans[tg[t-1]*NL + cur];
    }
  }
  __shared__ float ss[256]; __shared__ int sc[256];
  ss[threadIdx.x] = s; sc[threadIdx.x] = cnt;
  __syncthreads();
  for (int o = 128; o > 0; o >>= 1){
    if (threadIdx.x < o){ ss[threadIdx.x] += ss[threadIdx.x+o]; sc[threadIdx.x] += sc[threadIdx.x+o]; }
    __syncthreads();
  }
  if (threadIdx.x == 0){
    int len = sc[0];
    numlen[b]      = ss[0] + start[tg[0]] + endv[tg[len-1]];
    numlen[16 + b] = (float)len;
  }
}

// ---------------------------------------------------------------------------
// CRF forward (denominator), one wave per b; logits staged in LDS once.
// ---------------------------------------------------------------------------
__global__ __launch_bounds__(64) void crf_fwd(const float* __restrict__ logits,
    const int* __restrict__ targets, const float* __restrict__ trans,
    const float* __restrict__ start, const float* __restrict__ endv,
    float* __restrict__ denom)
{
  const int b = blockIdx.x, lane = threadIdx.x;
  __shared__ float el[SEQ*NL];   // 51.2 KB
  __shared__ float tr[NL*NL];
  for (int i = lane; i < NL*NL; i += 64) tr[i] = trans[i];
  {
    const float4* src = (const float4*)(logits + (size_t)b*SEQ*NL);
    float4* dst = (float4*)el;
    for (int i = lane; i < SEQ*NL/4; i += 64) dst[i] = src[i];
  }
  __syncthreads();
  const bool act = lane < NL;
  const int j = act ? lane : 0;
  float alpha = act ? (start[j] + el[j]) : -3e38f;
  const int* tg = targets + (size_t)b*SEQ;
  for (int t = 1; t < SEQ; t++){
    if (tg[t] < 0) break;
    float e = el[t*NL + j];
    float v[NL]; float mx = -3e38f;
    #pragma unroll
    for (int i = 0; i < NL; i++){
      float ai = __shfl(alpha, i);
      v[i] = ai + tr[i*NL + j];
      mx = fmaxf(mx, v[i]);
    }
    float sum = 0.f;
    #pragma unroll
    for (int i = 0; i < NL; i++) sum += __expf(v[i] - mx);
    float nxt = mx + __logf(sum) + e;
    if (act) alpha = nxt;
  }
  float x = act ? alpha + endv[j] : -3e38f;
  float m2 = x;
  #pragma unroll
  for (int off = 32; off >= 1; off >>= 1) m2 = fmaxf(m2, __shfl_xor(m2, off));
  float se = __expf(x - m2);
  #pragma unroll
  for (int off = 32; off >= 1; off >>= 1) se += __shfl_xor(se, off);
  if (lane == 0) denom[b] = m2 + __logf(se);
}

__global__ void crf_final(const float* __restrict__ numlen, const float* __restrict__ denom,
                          float* __restrict__ out)
{
  if (blockIdx.x == 0 && threadIdx.x == 0){
    float sn = 0.f, sl = 0.f;
    for (int b = 0; b < 16; b++){ sn += numlen[b] - denom[b]; sl += numlen[16+b]; }
    out[0] = -sn / sl;
  }
}

// ---------------------------------------------------------------------------
extern "C" void kernel_launch(void* const* d_in, const int* in_sizes, int n_in,
                              void* d_out, int out_size, void* d_ws, size_t ws_size,
                              hipStream_t stream)
{
  const float* hidden  = (const float*)d_in[0];
  const int*   targets = (const int*)  d_in[1];
  const float* w_ih[4] = {(const float*)d_in[2], (const float*)d_in[6], (const float*)d_in[10], (const float*)d_in[14]};
  const float* w_hh[4] = {(const float*)d_in[3], (const float*)d_in[7], (const float*)d_in[11], (const float*)d_in[15]};
  const float* b_ih[4] = {(const float*)d_in[4], (const float*)d_in[8], (const float*)d_in[12], (const float*)d_in[16]};
  const float* b_hh[4] = {(const float*)d_in[5], (const float*)d_in[9], (const float*)d_in[13], (const float*)d_in[17]};
  const float* clf_w = (const float*)d_in[18];
  const float* clf_b = (const float*)d_in[19];
  const float* trans = (const float*)d_in[20];
  const float* start = (const float*)d_in[21];
  const float* endv  = (const float*)d_in[22];

  // workspace layout (~127 MB)
  char* p = (char*)d_ws;
  auto alloc = [&](size_t bytes){ void* r = (void*)p; p += (bytes + 255) & ~(size_t)255; return r; };
  float* bias   = (float*)alloc((size_t)4*G4*4);
  u16*   xgp    = (u16*)  alloc((size_t)2*XGD*2);             // 100.7 MB repacked
  u16*   h1     = (u16*)  alloc((size_t)B*SEQ*2*HD*2);        // 25.2 MB (doubles as th)
  u64*   hgt    = (u64*)  alloc((size_t)2*2*6144*8);          // 192 KB tagged h ping-pong
  float* logits = (float*)alloc((size_t)B*SEQ*NL*4);
  float* numlen = (float*)alloc(32*4);
  float* denom  = (float*)alloc(16*4);
  if ((size_t)(p - (char*)d_ws) > ws_size) return;

  BPtrs bp;
  for (int i = 0; i < 4; i++){ bp.bi[i] = b_ih[i]; bp.bh[i] = b_hh[i]; }
  prep_bias<<<48, 256, 0, stream>>>(bp, bias);

  const dim3 ggrid(24, 64);
  const size_t hgt_bytes = (size_t)2*2*6144*8;

  // ---- layer 0 ----
  gemm_xg_mfma<float><<<ggrid, 256, 0, stream>>>(hidden, HD, w_ih[0], bias + 0*G4, xgp);
  gemm_xg_mfma<float><<<ggrid, 256, 0, stream>>>(hidden, HD, w_ih[1], bias + 1*G4, xgp + XGD);
  hipMemsetAsync(hgt, 0, hgt_bytes, stream);   // h(0)=0 with tag 0
  {
    const u16* a0 = xgp; const float* a1 = w_hh[0]; const float* a2 = w_hh[1];
    u64* a3 = hgt; u16* a4 = h1;
    void* args[] = { &a0, &a1, &a2, &a3, &a4 };
    hipLaunchCooperativeKernel(reinterpret_cast<void*>(&scan_kernel<0>),
                               dim3(2*NBLK), dim3(256), args, 0, stream);
  }

  // ---- layer 1 ----
  gemm_xg_mfma<u16><<<ggrid, 256, 0, stream>>>(h1, 2*HD, w_ih[2], bias + 2*G4, xgp);
  gemm_xg_mfma<u16><<<ggrid, 256, 0, stream>>>(h1, 2*HD, w_ih[3], bias + 3*G4, xgp + XGD);
  hipMemsetAsync(hgt, 0, hgt_bytes, stream);
  {
    const u16* a0 = xgp; const float* a1 = w_hh[2]; const float* a2 = w_hh[3];
    u64* a3 = hgt; u16* a4 = h1;
    void* args[] = { &a0, &a1, &a2, &a3, &a4 };
    hipLaunchCooperativeKernel(reinterpret_cast<void*>(&scan_kernel<1>),
                               dim3(2*NBLK), dim3(256), args, 0, stream);
  }

  // ---- classifier + CRF ----
  logits_kernel<<<1024, 256, 0, stream>>>(h1, clf_w, clf_b, logits);
  crf_num<<<16, 256, 0, stream>>>(logits, targets, trans, start, endv, numlen);
  crf_fwd<<<16, 64, 0, stream>>>(logits, targets, trans, start, endv, denom);
  crf_final<<<1, 64, 0, stream>>>(numlen, denom, (float*)d_out);
}

// Round 10
// 4082.535 us; speedup vs baseline: 2.4182x; 2.4182x over previous
//
#include <hip/hip_runtime.h>
#include <cstdint>
#include <cstddef>

// Problem constants
#define B   16
#define SEQ 512
#define HD  768
#define G4  3072   // 4*HD
#define NL  25
#define NBLK 96    // blocks per direction in the scan (8 h-units each)

using u16 = unsigned short;
using u32 = uint32_t;
using u64 = unsigned long long;

#define XGD ((size_t)96*SEQ*512)   // u16 elements per dir in repacked xg

__device__ __forceinline__ float bf2f(u16 u){
  union { float f; u32 i; } v; v.i = ((u32)u) << 16; return v.f;
}
__device__ __forceinline__ u16 f2bf(float f){
  union { float f; u32 i; } v; v.f = f;
  u32 r = v.i + 0x7FFFu + ((v.i >> 16) & 1u);  // RNE
  return (u16)(r >> 16);
}
__device__ __forceinline__ float asf(u32 u){ union { float f; u32 i; } v; v.i = u; return v.f; }
__device__ __forceinline__ float sigm(float x){ return 1.f/(1.f + __expf(-x)); }
__device__ __forceinline__ float tanhfast(float x){ return 1.f - 2.f/(__expf(2.f*x) + 1.f); }

typedef __attribute__((ext_vector_type(8))) short bf16x8;
typedef __attribute__((ext_vector_type(4))) float f32x4;

// stage 8 bf16 (16B) into LDS from either bf16 or fp32 global source
__device__ __forceinline__ void stage_to_lds(u16* dst, const u16* src){
  *(uint4*)dst = *(const uint4*)src;
}
__device__ __forceinline__ void stage_to_lds(u16* dst, const float* src){
  float4 a = *(const float4*)src;
  float4 b = *(const float4*)(src + 4);
  uint4 v;
  v.x = (u32)f2bf(a.x) | ((u32)f2bf(a.y) << 16);
  v.y = (u32)f2bf(a.z) | ((u32)f2bf(a.w) << 16);
  v.z = (u32)f2bf(b.x) | ((u32)f2bf(b.y) << 16);
  v.w = (u32)f2bf(b.z) | ((u32)f2bf(b.w) << 16);
  *(uint4*)dst = v;
}

// ---------------------------------------------------------------------------
// prep: bias[lid][g] = b_ih + b_hh
// ---------------------------------------------------------------------------
struct BPtrs { const float* bi[4]; const float* bh[4]; };

__global__ void prep_bias(BPtrs p, float* __restrict__ bias){
  int idx = blockIdx.x*blockDim.x + threadIdx.x;
  if (idx < 4*G4){
    int lid = idx / G4, g = idx % G4;
    bias[idx] = p.bi[lid][g] + p.bh[lid][g];
  }
}

// ---------------------------------------------------------------------------
// MFMA xg GEMM, BK=64 (half the barriers of BK=32), writes xg REPACKED
// for the scan: dst[js8][t][g][b][jl8]  (js8 = j>>3, jl8 = j&7).
// M=8192, N=3072, K in {768,1536}. 128x128 tile, 4 waves, 16x16x32 MFMA.
// ---------------------------------------------------------------------------
template<typename AT>
__global__ __launch_bounds__(256) void gemm_xg_mfma(const AT* __restrict__ A, int K,
    const float* __restrict__ W, const float* __restrict__ bias, u16* __restrict__ out)
{
  __shared__ u16 As[128][72];
  __shared__ u16 Bs[128][72];
  const int tid = threadIdx.x;
  const int bm = blockIdx.y * 128;
  const int bn = blockIdx.x * 128;
  const int wid = tid >> 6, lane = tid & 63;
  const int wr = wid >> 1, wc = wid & 1;
  const int kq = lane >> 4, rl = lane & 15;

  f32x4 acc[4][4];
  #pragma unroll
  for (int mf = 0; mf < 4; mf++)
    #pragma unroll
    for (int nf = 0; nf < 4; nf++) acc[mf][nf] = (f32x4){0.f,0.f,0.f,0.f};

  for (int k0 = 0; k0 < K; k0 += 64){
    #pragma unroll
    for (int u = 0; u < 4; u++){
      int c = tid + u*256;          // 1024 chunks of 8 u16 per tile
      int r = c >> 3, q = c & 7;
      stage_to_lds(&As[r][q*8], A + (size_t)(bm + r)*K + k0 + q*8);
      stage_to_lds(&Bs[r][q*8], W + (size_t)(bn + r)*K + k0 + q*8);
    }
    __syncthreads();
    #pragma unroll
    for (int sub = 0; sub < 2; sub++){
      bf16x8 af4[4], bfr4[4];
      #pragma unroll
      for (int mf = 0; mf < 4; mf++)
        af4[mf]  = *(const bf16x8*)&As[wr*64 + mf*16 + rl][sub*32 + kq*8];
      #pragma unroll
      for (int nf = 0; nf < 4; nf++)
        bfr4[nf] = *(const bf16x8*)&Bs[wc*64 + nf*16 + rl][sub*32 + kq*8];
      #pragma unroll
      for (int mf = 0; mf < 4; mf++)
        #pragma unroll
        for (int nf = 0; nf < 4; nf++)
          acc[mf][nf] = __builtin_amdgcn_mfma_f32_16x16x32_bf16(af4[mf], bfr4[nf], acc[mf][nf], 0, 0, 0);
    }
    __syncthreads();
  }

  float bv[4];
  size_t coloff[4];
  #pragma unroll
  for (int nf = 0; nf < 4; nf++){
    int n = bn + wc*64 + nf*16 + rl;
    bv[nf] = bias[n];
    int g = n / 768, j = n - g*768;
    coloff[nf] = (size_t)(j >> 3)*262144 + (size_t)g*128 + (j & 7);
  }
  #pragma unroll
  for (int mf = 0; mf < 4; mf++){
    #pragma unroll
    for (int i = 0; i < 4; i++){
      int row = bm + wr*64 + mf*16 + kq*4 + i;     // = b*SEQ + t
      int b = row >> 9, t = row & 511;
      size_t rowoff = (size_t)t*512 + (size_t)b*8;
      #pragma unroll
      for (int nf = 0; nf < 4; nf++)
        out[coloff[nf] + rowoff] = f2bf(acc[mf][nf][i] + bv[nf]);
    }
  }
}

// ---------------------------------------------------------------------------
// Persistent LSTM scan — R5 PROTOCOL (measured 3.07 us/step), only change:
// xg prefetch reads the repacked layout (address-only; verified R6-R9).
// 192 blocks x 256 thr (4 waves). dir = bid/96, js = bid%96 (8 h-units).
// Waves split K=768 into 4x192. Per step:
//   xg prefetch -> [s>0: tid<96 poll own flag w/ s_sleep, syncthreads] ->
//   B-frags (h) direct to regs (agent atomic u64 pairs) -> 12 MFMA ->
//   red write -> syncthreads -> tid<128: gates -> publish h pairs [b][k] ->
//   syncthreads (drains vmcnt) -> tid==0 flag=s+1 -> hout off critical path.
// Ping-pong depth 2 safe: flags>=s for all => all step s-1 reads retired.
// ---------------------------------------------------------------------------
template<int LAYER>
__global__ __launch_bounds__(256, 1) void scan_kernel(
    const u16* __restrict__ xgp,     // [dir][js8][t][g][b][jl8]
    const float* __restrict__ whh_f, // [3072][768]
    const float* __restrict__ whh_r,
    u16* __restrict__ hgbu,          // [2 ping][2 dir][16 b][768 k] bf16
    u32* __restrict__ flags,         // [2 dir][NBLK], zeroed
    u16* __restrict__ hout)          // [b*SEQ+t][1536]
{
  __shared__ float red[32*16*4];   // [j_local][b][wave]
  __shared__ float cL[128];        // c state [jh_l][b]

  const int tid  = threadIdx.x;
  const int dir  = blockIdx.x / NBLK;
  const int js   = blockIdx.x % NBLK;
  const int w    = tid >> 6;
  const int lane = tid & 63;
  const int lr   = lane & 15;   // A-row (j) / B-col (b)
  const int lq   = lane >> 4;   // k-octet selector

  const float* Wsrc = dir ? whh_r : whh_f;

  // one-time A-frag preload: af[m][c] covers j = m*16+lr, k = w*192+c*32+lq*8
  bf16x8 af[2][6];
  #pragma unroll
  for (int m = 0; m < 2; m++){
    int j_local = m*16 + lr;
    int j_glob  = (j_local >> 3)*768 + js*8 + (j_local & 7);  // gate-major rows
    const float* rowp = Wsrc + (size_t)j_glob*HD;
    #pragma unroll
    for (int c = 0; c < 6; c++){
      int k = w*192 + c*32 + lq*8;
      float4 a  = *(const float4*)(rowp + k);
      float4 b4 = *(const float4*)(rowp + k + 4);
      union { u32 u[4]; bf16x8 v; } t;
      t.u[0] = (u32)f2bf(a.x)  | ((u32)f2bf(a.y)  << 16);
      t.u[1] = (u32)f2bf(a.z)  | ((u32)f2bf(a.w)  << 16);
      t.u[2] = (u32)f2bf(b4.x) | ((u32)f2bf(b4.y) << 16);
      t.u[3] = (u32)f2bf(b4.z) | ((u32)f2bf(b4.w) << 16);
      af[m][c] = t.v;
    }
  }
  if (tid < 128) cL[tid] = 0.f;
  __syncthreads();

  const int jh_l = tid >> 4;    // 0..7 (valid for tid<128)
  const int b_g  = tid & 15;
  u32* myflag = flags + dir*NBLK;

  for (int s = 0; s < SEQ; s++){
    const int t_seq = dir ? (SEQ-1-s) : s;

    // xg prefetch BEFORE the poll (repacked: contiguous 1KB/block-step)
    float xgv[4];
    if (tid < 128){
      const u16* xp = xgp + (size_t)dir*XGD + (size_t)js*262144
                    + (size_t)t_seq*512 + b_g*8 + jh_l;
      #pragma unroll
      for (int g = 0; g < 4; g++) xgv[g] = bf2f(xp[g*128]);
    }

    // wait for all 96 producer blocks of this dir to publish H[s]
    if (s > 0){
      if (tid < NBLK){
        while (__hip_atomic_load(&myflag[tid], __ATOMIC_RELAXED, __HIP_MEMORY_SCOPE_AGENT) < (u32)s)
          __builtin_amdgcn_s_sleep(1);
      }
      __syncthreads();
    }

    // B-frags (h) direct to registers from the coherent point
    const u16* hb = hgbu + (size_t)((s&1)*2 + dir)*(16*768) + lr*768;
    u64 bq[6][2];
    #pragma unroll
    for (int c = 0; c < 6; c++){
      const u64* p = (const u64*)(hb + w*192 + c*32 + lq*8);
      bq[c][0] = __hip_atomic_load(p,     __ATOMIC_RELAXED, __HIP_MEMORY_SCOPE_AGENT);
      bq[c][1] = __hip_atomic_load(p + 1, __ATOMIC_RELAXED, __HIP_MEMORY_SCOPE_AGENT);
    }

    f32x4 acc0 = (f32x4){0.f,0.f,0.f,0.f};
    f32x4 acc1 = (f32x4){0.f,0.f,0.f,0.f};
    #pragma unroll
    for (int c = 0; c < 6; c++){
      union { u64 q[2]; bf16x8 v; } bu;
      bu.q[0] = bq[c][0]; bu.q[1] = bq[c][1];
      acc0 = __builtin_amdgcn_mfma_f32_16x16x32_bf16(af[0][c], bu.v, acc0, 0, 0, 0);
      acc1 = __builtin_amdgcn_mfma_f32_16x16x32_bf16(af[1][c], bu.v, acc1, 0, 0, 0);
    }

    // cross-wave K reduce via LDS: D[j = lq*4+i (+16 for acc1)][b = lr]
    #pragma unroll
    for (int i = 0; i < 4; i++){
      red[(( 0 + lq*4 + i)*16 + lr)*4 + w] = acc0[i];
      red[((16 + lq*4 + i)*16 + lr)*4 + w] = acc1[i];
    }
    __syncthreads();

    const bool more = (s + 1 < SEQ);
    u32 opair = 0;
    if (tid < 128){
      float gs[4];
      #pragma unroll
      for (int g = 0; g < 4; g++){
        const float4 r4 = *(const float4*)&red[((g*8 + jh_l)*16 + b_g)*4];
        gs[g] = r4.x + r4.y + r4.z + r4.w + xgv[g];
      }
      float c  = cL[tid];
      float ct = sigm(gs[1])*c + sigm(gs[0])*tanhfast(gs[2]);
      float h  = sigm(gs[3])*tanhfast(ct);
      cL[tid] = ct;

      // pack pairs along k via shfl (partner tid^16 = jh_l^1 at same b)
      u32 hb16 = (u32)f2bf(h);
      u32 hoth = (u32)__shfl_xor((int)hb16, 16);
      float hw = (LAYER == 0) ? h : tanhfast(h);
      u32 ob16 = (u32)f2bf(hw);
      u32 ooth = (u32)__shfl_xor((int)ob16, 16);
      opair = (ob16 & 0xffffu) | (ooth << 16);

      if (more && (tid & 16) == 0){
        u32 pair = (hb16 & 0xffffu) | (hoth << 16);
        u16* hdst = hgbu + (size_t)(((s+1)&1)*2 + dir)*(16*768) + b_g*768 + js*8 + jh_l;
        __hip_atomic_store((u32*)hdst, pair, __ATOMIC_RELAXED, __HIP_MEMORY_SCOPE_AGENT);
      }
    }
    if (more){
      __syncthreads();   // drains vmcnt -> h publish visible before flag
      if (tid == 0)
        __hip_atomic_store(&myflag[js], (u32)(s+1), __ATOMIC_RELAXED, __HIP_MEMORY_SCOPE_AGENT);
    }
    // hout write AFTER the flag: off the inter-block critical path
    if (tid < 128 && (tid & 16) == 0){
      u16* od = hout + ((size_t)b_g*SEQ + t_seq)*1536 + dir*HD + js*8 + jh_l;
      *(u32*)od = opair;
    }
  }
}

// ---------------------------------------------------------------------------
// logits[row][l] = tanh(h2)[row] . clf_w[l] + clf_b[l]  (th already tanh'd)
// ---------------------------------------------------------------------------
__global__ __launch_bounds__(256) void logits_kernel(const u16* __restrict__ th,
    const float* __restrict__ clf_w, const float* __restrict__ clf_b,
    float* __restrict__ logits)
{
  __shared__ u16 xl[8*1536];
  const int tid = threadIdx.x;
  const int row0 = blockIdx.x * 8;
  {
    const uint4* src = (const uint4*)(th + (size_t)row0*1536);
    uint4* dst = (uint4*)xl;
    #pragma unroll
    for (int i = 0; i < 6; i++) dst[i*256 + tid] = src[i*256 + tid];
  }
  __syncthreads();
  const int r = tid >> 5, l = tid & 31;
  if (l < NL){
    float acc = clf_b[l];
    const float* wr = clf_w + (size_t)l*1536;
    #pragma unroll 2
    for (int kk = 0; kk < 192; kk++){
      uint4 xv = *(const uint4*)&xl[r*1536 + kk*8];
      float4 w0 = *(const float4*)(wr + kk*8);
      float4 w1 = *(const float4*)(wr + kk*8 + 4);
      acc = fmaf(asf(xv.x<<16), w0.x, acc); acc = fmaf(asf(xv.x&0xffff0000u), w0.y, acc);
      acc = fmaf(asf(xv.y<<16), w0.z, acc); acc = fmaf(asf(xv.y&0xffff0000u), w0.w, acc);
      acc = fmaf(asf(xv.z<<16), w1.x, acc); acc = fmaf(asf(xv.z&0xffff0000u), w1.y, acc);
      acc = fmaf(asf(xv.w<<16), w1.z, acc); acc = fmaf(asf(xv.w&0xffff0000u), w1.w, acc);
    }
    logits[(size_t)(row0 + r)*NL + l] = acc;
  }
}

// ---------------------------------------------------------------------------
// CRF numerator + lengths (per b)
// ---------------------------------------------------------------------------
__global__ __launch_bounds__(256) void crf_num(const float* __restrict__ logits,
    const int* __restrict__ targets, const float* __restrict__ trans,
    const float* __restrict__ start, const float* __restrict__ endv,
    float* __restrict__ numlen)
{
  const int b = blockIdx.x;
  const int* tg = targets + (size_t)b*SEQ;
  float s = 0.f; int cnt = 0;
  for (int t = threadIdx.x; t < SEQ; t += 256){
    int cur = tg[t];
    if (cur >= 0){
      cnt++;
      float e = logits[((size_t)b*SEQ + t)*NL + cur];
      s += e;
      if (t > 0) s += trans[tg[t-1]*NL + cur];
    }
  }
  __shared__ float ss[256]; __shared__ int sc[256];
  ss[threadIdx.x] = s; sc[threadIdx.x] = cnt;
  __syncthreads();
  for (int o = 128; o > 0; o >>= 1){
    if (threadIdx.x < o){ ss[threadIdx.x] += ss[threadIdx.x+o]; sc[threadIdx.x] += sc[threadIdx.x+o]; }
    __syncthreads();
  }
  if (threadIdx.x == 0){
    int len = sc[0];
    numlen[b]      = ss[0] + start[tg[0]] + endv[tg[len-1]];
    numlen[16 + b] = (float)len;
  }
}

// ---------------------------------------------------------------------------
// CRF forward (denominator), one wave per b; logits staged in LDS once.
// ---------------------------------------------------------------------------
__global__ __launch_bounds__(64) void crf_fwd(const float* __restrict__ logits,
    const int* __restrict__ targets, const float* __restrict__ trans,
    const float* __restrict__ start, const float* __restrict__ endv,
    float* __restrict__ denom)
{
  const int b = blockIdx.x, lane = threadIdx.x;
  __shared__ float el[SEQ*NL];   // 51.2 KB
  __shared__ float tr[NL*NL];
  for (int i = lane; i < NL*NL; i += 64) tr[i] = trans[i];
  {
    const float4* src = (const float4*)(logits + (size_t)b*SEQ*NL);
    float4* dst = (float4*)el;
    for (int i = lane; i < SEQ*NL/4; i += 64) dst[i] = src[i];
  }
  __syncthreads();
  const bool act = lane < NL;
  const int j = act ? lane : 0;
  float alpha = act ? (start[j] + el[j]) : -3e38f;
  const int* tg = targets + (size_t)b*SEQ;
  for (int t = 1; t < SEQ; t++){
    if (tg[t] < 0) break;
    float e = el[t*NL + j];
    float v[NL]; float mx = -3e38f;
    #pragma unroll
    for (int i = 0; i < NL; i++){
      float ai = __shfl(alpha, i);
      v[i] = ai + tr[i*NL + j];
      mx = fmaxf(mx, v[i]);
    }
    float sum = 0.f;
    #pragma unroll
    for (int i = 0; i < NL; i++) sum += __expf(v[i] - mx);
    float nxt = mx + __logf(sum) + e;
    if (act) alpha = nxt;
  }
  float x = act ? alpha + endv[j] : -3e38f;
  float m2 = x;
  #pragma unroll
  for (int off = 32; off >= 1; off >>= 1) m2 = fmaxf(m2, __shfl_xor(m2, off));
  float se = __expf(x - m2);
  #pragma unroll
  for (int off = 32; off >= 1; off >>= 1) se += __shfl_xor(se, off);
  if (lane == 0) denom[b] = m2 + __logf(se);
}

__global__ void crf_final(const float* __restrict__ numlen, const float* __restrict__ denom,
                          float* __restrict__ out)
{
  if (blockIdx.x == 0 && threadIdx.x == 0){
    float sn = 0.f, sl = 0.f;
    for (int b = 0; b < 16; b++){ sn += numlen[b] - denom[b]; sl += numlen[16+b]; }
    out[0] = -sn / sl;
  }
}

// ---------------------------------------------------------------------------
extern "C" void kernel_launch(void* const* d_in, const int* in_sizes, int n_in,
                              void* d_out, int out_size, void* d_ws, size_t ws_size,
                              hipStream_t stream)
{
  const float* hidden  = (const float*)d_in[0];
  const int*   targets = (const int*)  d_in[1];
  const float* w_ih[4] = {(const float*)d_in[2], (const float*)d_in[6], (const float*)d_in[10], (const float*)d_in[14]};
  const float* w_hh[4] = {(const float*)d_in[3], (const float*)d_in[7], (const float*)d_in[11], (const float*)d_in[15]};
  const float* b_ih[4] = {(const float*)d_in[4], (const float*)d_in[8], (const float*)d_in[12], (const float*)d_in[16]};
  const float* b_hh[4] = {(const float*)d_in[5], (const float*)d_in[9], (const float*)d_in[13], (const float*)d_in[17]};
  const float* clf_w = (const float*)d_in[18];
  const float* clf_b = (const float*)d_in[19];
  const float* trans = (const float*)d_in[20];
  const float* start = (const float*)d_in[21];
  const float* endv  = (const float*)d_in[22];

  // workspace layout (~127 MB)
  char* p = (char*)d_ws;
  auto alloc = [&](size_t bytes){ void* r = (void*)p; p += (bytes + 255) & ~(size_t)255; return r; };
  float* bias   = (float*)alloc((size_t)4*G4*4);
  u16*   xgp    = (u16*)  alloc((size_t)2*XGD*2);             // 100.7 MB repacked
  u16*   h1     = (u16*)  alloc((size_t)B*SEQ*2*HD*2);        // 25.2 MB (doubles as th)
  u16*   hgbu   = (u16*)  alloc((size_t)2*2*16*768*2);        // 96 KB h ping-pong [ping][dir][b][k]
  u32*   flags  = (u32*)  alloc((size_t)2*NBLK*4);            // per-block flags
  float* logits = (float*)alloc((size_t)B*SEQ*NL*4);
  float* numlen = (float*)alloc(32*4);
  float* denom  = (float*)alloc(16*4);
  if ((size_t)(p - (char*)d_ws) > ws_size) return;

  BPtrs bp;
  for (int i = 0; i < 4; i++){ bp.bi[i] = b_ih[i]; bp.bh[i] = b_hh[i]; }
  prep_bias<<<48, 256, 0, stream>>>(bp, bias);

  const dim3 ggrid(24, 64);
  const size_t hgb_bytes = (size_t)2*2*16*768*2;
  const size_t flg_bytes = (size_t)2*NBLK*4;

  // ---- layer 0 ----
  gemm_xg_mfma<float><<<ggrid, 256, 0, stream>>>(hidden, HD, w_ih[0], bias + 0*G4, xgp);
  gemm_xg_mfma<float><<<ggrid, 256, 0, stream>>>(hidden, HD, w_ih[1], bias + 1*G4, xgp + XGD);
  hipMemsetAsync(hgbu, 0, hgb_bytes, stream);
  hipMemsetAsync(flags, 0, flg_bytes, stream);
  {
    const u16* a0 = xgp; const float* a1 = w_hh[0]; const float* a2 = w_hh[1];
    u16* a3 = hgbu; u32* a4 = flags; u16* a5 = h1;
    void* args[] = { &a0, &a1, &a2, &a3, &a4, &a5 };
    hipLaunchCooperativeKernel(reinterpret_cast<void*>(&scan_kernel<0>),
                               dim3(2*NBLK), dim3(256), args, 0, stream);
  }

  // ---- layer 1 ----
  gemm_xg_mfma<u16><<<ggrid, 256, 0, stream>>>(h1, 2*HD, w_ih[2], bias + 2*G4, xgp);
  gemm_xg_mfma<u16><<<ggrid, 256, 0, stream>>>(h1, 2*HD, w_ih[3], bias + 3*G4, xgp + XGD);
  hipMemsetAsync(hgbu, 0, hgb_bytes, stream);
  hipMemsetAsync(flags, 0, flg_bytes, stream);
  {
    const u16* a0 = xgp; const float* a1 = w_hh[2]; const float* a2 = w_hh[3];
    u16* a3 = hgbu; u32* a4 = flags; u16* a5 = h1;
    void* args[] = { &a0, &a1, &a2, &a3, &a4, &a5 };
    hipLaunchCooperativeKernel(reinterpret_cast<void*>(&scan_kernel<1>),
                               dim3(2*NBLK), dim3(256), args, 0, stream);
  }

  // ---- classifier + CRF ----
  logits_kernel<<<1024, 256, 0, stream>>>(h1, clf_w, clf_b, logits);
  crf_num<<<16, 256, 0, stream>>>(logits, targets, trans, start, endv, numlen);
  crf_fwd<<<16, 64, 0, stream>>>(logits, targets, trans, start, endv, denom);
  crf_final<<<1, 64, 0, stream>>>(numlen, denom, (float*)d_out);
}

// Round 11
// 3979.815 us; speedup vs baseline: 2.4806x; 1.0258x over previous
//
#include <hip/hip_runtime.h>
#include <cstdint>
#include <cstddef>

// Problem constants
#define B   16
#define SEQ 512
#define HD  768
#define G4  3072   // 4*HD
#define NL  25
#define NBLK 96    // blocks per direction in the scan (8 h-units each)

using u16 = unsigned short;
using u32 = uint32_t;
using u64 = unsigned long long;

#define XGD ((size_t)96*SEQ*512)   // u16 elements per dir in repacked xg

__device__ __forceinline__ float bf2f(u16 u){
  union { float f; u32 i; } v; v.i = ((u32)u) << 16; return v.f;
}
__device__ __forceinline__ u16 f2bf(float f){
  union { float f; u32 i; } v; v.f = f;
  u32 r = v.i + 0x7FFFu + ((v.i >> 16) & 1u);  // RNE
  return (u16)(r >> 16);
}
__device__ __forceinline__ float asf(u32 u){ union { float f; u32 i; } v; v.i = u; return v.f; }
__device__ __forceinline__ float sigm(float x){ return 1.f/(1.f + __expf(-x)); }
__device__ __forceinline__ float tanhfast(float x){ return 1.f - 2.f/(__expf(2.f*x) + 1.f); }

typedef __attribute__((ext_vector_type(8))) short bf16x8;
typedef __attribute__((ext_vector_type(4))) float f32x4;

// async global->LDS, 16B per lane; lds dest must be wave-uniform base (HW
// scatters lane i at base + i*16). Counts against vmcnt; __syncthreads drains.
__device__ __forceinline__ void gload16(const u16* g, u16* l){
  __builtin_amdgcn_global_load_lds(
      (const __attribute__((address_space(1))) void*)g,
      (__attribute__((address_space(3))) void*)l, 16, 0, 0);
}

// VALU stage of 8 bf16 (16B) from fp32 global source (layer-0 A path)
__device__ __forceinline__ void stage_to_lds(u16* dst, const float* src){
  float4 a = *(const float4*)src;
  float4 b = *(const float4*)(src + 4);
  uint4 v;
  v.x = (u32)f2bf(a.x) | ((u32)f2bf(a.y) << 16);
  v.y = (u32)f2bf(a.z) | ((u32)f2bf(a.w) << 16);
  v.z = (u32)f2bf(b.x) | ((u32)f2bf(b.y) << 16);
  v.w = (u32)f2bf(b.z) | ((u32)f2bf(b.w) << 16);
  *(uint4*)dst = v;
}

// ---------------------------------------------------------------------------
// prep: bias[lid][g] = b_ih + b_hh
// ---------------------------------------------------------------------------
struct BPtrs { const float* bi[4]; const float* bh[4]; };

__global__ void prep_bias(BPtrs p, float* __restrict__ bias){
  int idx = blockIdx.x*blockDim.x + threadIdx.x;
  if (idx < 4*G4){
    int lid = idx / G4, g = idx % G4;
    bias[idx] = p.bi[lid][g] + p.bh[lid][g];
  }
}

// fp32 -> bf16 bulk convert (n8 groups of 8 elements)
__global__ void conv_bf16(const float* __restrict__ src, u16* __restrict__ dst, int n8){
  for (int i = blockIdx.x*blockDim.x + threadIdx.x; i < n8; i += gridDim.x*blockDim.x)
    stage_to_lds(dst + (size_t)i*8, src + (size_t)i*8);
}

// ---------------------------------------------------------------------------
// Tile staging helpers. Tile = 128 rows x 64 bf16 cols = 1024 chunks of 16B.
// Chunk position c = row*8 + q. XOR swizzle (T2/m173): LDS stays LINEAR
// (gload requirement); position (r,q) holds DATA chunk (r, q^(r&7));
// frag reads use the same XOR -> bank-group = q'*4 only -> 2-way (free).
// ---------------------------------------------------------------------------
__device__ __forceinline__ void stage_tile(u16* Ls, const u16* A, size_t ldk,
                                           int base_row, int k0, int wid, int lane){
  #pragma unroll
  for (int i = 0; i < 4; i++){
    int cbase = i*256 + wid*64;          // wave-uniform
    int c  = cbase + lane;
    int rs = c >> 3, qs = c & 7;
    int qg = qs ^ (rs & 7);
    gload16(A + (size_t)(base_row + rs)*ldk + k0 + qg*8, Ls + (size_t)cbase*8);
  }
}
__device__ __forceinline__ void stage_tile(u16* Ls, const float* A, size_t ldk,
                                           int base_row, int k0, int wid, int lane){
  const int tid = wid*64 + lane;
  #pragma unroll
  for (int i = 0; i < 4; i++){
    int c  = i*256 + tid;
    int rs = c >> 3, qs = c & 7;
    int qg = qs ^ (rs & 7);
    stage_to_lds(Ls + rs*64 + qs*8, A + (size_t)(base_row + rs)*ldk + k0 + qg*8);
  }
}

// ---------------------------------------------------------------------------
// MFMA xg GEMM, BK=64, B (weights) pre-converted bf16 staged via
// global_load_lds; A is fp32 (layer 0, VALU cvt) or bf16 (layer 1, gload).
// Writes xg REPACKED for the scan: dst[js8][t][g][b][jl8].
// M=8192, N=3072, K in {768,1536}. 128x128 tile, 4 waves, 16x16x32 MFMA.
// ---------------------------------------------------------------------------
template<typename AT>
__global__ __launch_bounds__(256) void gemm_xg_mfma(const AT* __restrict__ A, int K,
    const u16* __restrict__ W, const float* __restrict__ bias, u16* __restrict__ out)
{
  __shared__ u16 As[128*64];
  __shared__ u16 Bs[128*64];
  const int tid = threadIdx.x;
  const int bm = blockIdx.y * 128;
  const int bn = blockIdx.x * 128;
  const int wid = tid >> 6, lane = tid & 63;
  const int wr = wid >> 1, wc = wid & 1;
  const int kq = lane >> 4, rl = lane & 15;

  f32x4 acc[4][4];
  #pragma unroll
  for (int mf = 0; mf < 4; mf++)
    #pragma unroll
    for (int nf = 0; nf < 4; nf++) acc[mf][nf] = (f32x4){0.f,0.f,0.f,0.f};

  for (int k0 = 0; k0 < K; k0 += 64){
    stage_tile(Bs, W, (size_t)K, bn, k0, wid, lane);
    stage_tile(As, A, (size_t)K, bm, k0, wid, lane);
    __syncthreads();     // drains vmcnt (gload) + lgkm; tiles ready
    #pragma unroll
    for (int sub = 0; sub < 2; sub++){
      bf16x8 af4[4], bfr4[4];
      #pragma unroll
      for (int mf = 0; mf < 4; mf++){
        int r = wr*64 + mf*16 + rl;
        af4[mf]  = *(const bf16x8*)&As[r*64 + (((sub<<2)|kq) ^ (r & 7))*8];
      }
      #pragma unroll
      for (int nf = 0; nf < 4; nf++){
        int r = wc*64 + nf*16 + rl;
        bfr4[nf] = *(const bf16x8*)&Bs[r*64 + (((sub<<2)|kq) ^ (r & 7))*8];
      }
      #pragma unroll
      for (int mf = 0; mf < 4; mf++)
        #pragma unroll
        for (int nf = 0; nf < 4; nf++)
          acc[mf][nf] = __builtin_amdgcn_mfma_f32_16x16x32_bf16(af4[mf], bfr4[nf], acc[mf][nf], 0, 0, 0);
    }
    __syncthreads();
  }

  float bv[4];
  size_t coloff[4];
  #pragma unroll
  for (int nf = 0; nf < 4; nf++){
    int n = bn + wc*64 + nf*16 + rl;
    bv[nf] = bias[n];
    int g = n / 768, j = n - g*768;
    coloff[nf] = (size_t)(j >> 3)*262144 + (size_t)g*128 + (j & 7);
  }
  #pragma unroll
  for (int mf = 0; mf < 4; mf++){
    #pragma unroll
    for (int i = 0; i < 4; i++){
      int row = bm + wr*64 + mf*16 + kq*4 + i;     // = b*SEQ + t
      int b = row >> 9, t = row & 511;
      size_t rowoff = (size_t)t*512 + (size_t)b*8;
      #pragma unroll
      for (int nf = 0; nf < 4; nf++)
        out[coloff[nf] + rowoff] = f2bf(acc[mf][nf][i] + bv[nf]);
    }
  }
}

// ---------------------------------------------------------------------------
// Persistent LSTM scan — R10 kernel, byte-identical (measured 1561 us).
// ---------------------------------------------------------------------------
template<int LAYER>
__global__ __launch_bounds__(256, 1) void scan_kernel(
    const u16* __restrict__ xgp,     // [dir][js8][t][g][b][jl8]
    const float* __restrict__ whh_f, // [3072][768]
    const float* __restrict__ whh_r,
    u16* __restrict__ hgbu,          // [2 ping][2 dir][16 b][768 k] bf16
    u32* __restrict__ flags,         // [2 dir][NBLK], zeroed
    u16* __restrict__ hout)          // [b*SEQ+t][1536]
{
  __shared__ float red[32*16*4];   // [j_local][b][wave]
  __shared__ float cL[128];        // c state [jh_l][b]

  const int tid  = threadIdx.x;
  const int dir  = blockIdx.x / NBLK;
  const int js   = blockIdx.x % NBLK;
  const int w    = tid >> 6;
  const int lane = tid & 63;
  const int lr   = lane & 15;   // A-row (j) / B-col (b)
  const int lq   = lane >> 4;   // k-octet selector

  const float* Wsrc = dir ? whh_r : whh_f;

  // one-time A-frag preload: af[m][c] covers j = m*16+lr, k = w*192+c*32+lq*8
  bf16x8 af[2][6];
  #pragma unroll
  for (int m = 0; m < 2; m++){
    int j_local = m*16 + lr;
    int j_glob  = (j_local >> 3)*768 + js*8 + (j_local & 7);  // gate-major rows
    const float* rowp = Wsrc + (size_t)j_glob*HD;
    #pragma unroll
    for (int c = 0; c < 6; c++){
      int k = w*192 + c*32 + lq*8;
      float4 a  = *(const float4*)(rowp + k);
      float4 b4 = *(const float4*)(rowp + k + 4);
      union { u32 u[4]; bf16x8 v; } t;
      t.u[0] = (u32)f2bf(a.x)  | ((u32)f2bf(a.y)  << 16);
      t.u[1] = (u32)f2bf(a.z)  | ((u32)f2bf(a.w)  << 16);
      t.u[2] = (u32)f2bf(b4.x) | ((u32)f2bf(b4.y) << 16);
      t.u[3] = (u32)f2bf(b4.z) | ((u32)f2bf(b4.w) << 16);
      af[m][c] = t.v;
    }
  }
  if (tid < 128) cL[tid] = 0.f;
  __syncthreads();

  const int jh_l = tid >> 4;    // 0..7 (valid for tid<128)
  const int b_g  = tid & 15;
  u32* myflag = flags + dir*NBLK;

  for (int s = 0; s < SEQ; s++){
    const int t_seq = dir ? (SEQ-1-s) : s;

    // xg prefetch BEFORE the poll (repacked: contiguous 1KB/block-step)
    float xgv[4];
    if (tid < 128){
      const u16* xp = xgp + (size_t)dir*XGD + (size_t)js*262144
                    + (size_t)t_seq*512 + b_g*8 + jh_l;
      #pragma unroll
      for (int g = 0; g < 4; g++) xgv[g] = bf2f(xp[g*128]);
    }

    // wait for all 96 producer blocks of this dir to publish H[s]
    if (s > 0){
      if (tid < NBLK){
        while (__hip_atomic_load(&myflag[tid], __ATOMIC_RELAXED, __HIP_MEMORY_SCOPE_AGENT) < (u32)s)
          __builtin_amdgcn_s_sleep(1);
      }
      __syncthreads();
    }

    // B-frags (h) direct to registers from the coherent point
    const u16* hb = hgbu + (size_t)((s&1)*2 + dir)*(16*768) + lr*768;
    u64 bq[6][2];
    #pragma unroll
    for (int c = 0; c < 6; c++){
      const u64* p = (const u64*)(hb + w*192 + c*32 + lq*8);
      bq[c][0] = __hip_atomic_load(p,     __ATOMIC_RELAXED, __HIP_MEMORY_SCOPE_AGENT);
      bq[c][1] = __hip_atomic_load(p + 1, __ATOMIC_RELAXED, __HIP_MEMORY_SCOPE_AGENT);
    }

    f32x4 acc0 = (f32x4){0.f,0.f,0.f,0.f};
    f32x4 acc1 = (f32x4){0.f,0.f,0.f,0.f};
    #pragma unroll
    for (int c = 0; c < 6; c++){
      union { u64 q[2]; bf16x8 v; } bu;
      bu.q[0] = bq[c][0]; bu.q[1] = bq[c][1];
      acc0 = __builtin_amdgcn_mfma_f32_16x16x32_bf16(af[0][c], bu.v, acc0, 0, 0, 0);
      acc1 = __builtin_amdgcn_mfma_f32_16x16x32_bf16(af[1][c], bu.v, acc1, 0, 0, 0);
    }

    // cross-wave K reduce via LDS: D[j = lq*4+i (+16 for acc1)][b = lr]
    #pragma unroll
    for (int i = 0; i < 4; i++){
      red[(( 0 + lq*4 + i)*16 + lr)*4 + w] = acc0[i];
      red[((16 + lq*4 + i)*16 + lr)*4 + w] = acc1[i];
    }
    __syncthreads();

    const bool more = (s + 1 < SEQ);
    u32 opair = 0;
    if (tid < 128){
      float gs[4];
      #pragma unroll
      for (int g = 0; g < 4; g++){
        const float4 r4 = *(const float4*)&red[((g*8 + jh_l)*16 + b_g)*4];
        gs[g] = r4.x + r4.y + r4.z + r4.w + xgv[g];
      }
      float c  = cL[tid];
      float ct = sigm(gs[1])*c + sigm(gs[0])*tanhfast(gs[2]);
      float h  = sigm(gs[3])*tanhfast(ct);
      cL[tid] = ct;

      // pack pairs along k via shfl (partner tid^16 = jh_l^1 at same b)
      u32 hb16 = (u32)f2bf(h);
      u32 hoth = (u32)__shfl_xor((int)hb16, 16);
      float hw = (LAYER == 0) ? h : tanhfast(h);
      u32 ob16 = (u32)f2bf(hw);
      u32 ooth = (u32)__shfl_xor((int)ob16, 16);
      opair = (ob16 & 0xffffu) | (ooth << 16);

      if (more && (tid & 16) == 0){
        u32 pair = (hb16 & 0xffffu) | (hoth << 16);
        u16* hdst = hgbu + (size_t)(((s+1)&1)*2 + dir)*(16*768) + b_g*768 + js*8 + jh_l;
        __hip_atomic_store((u32*)hdst, pair, __ATOMIC_RELAXED, __HIP_MEMORY_SCOPE_AGENT);
      }
    }
    if (more){
      __syncthreads();   // drains vmcnt -> h publish visible before flag
      if (tid == 0)
        __hip_atomic_store(&myflag[js], (u32)(s+1), __ATOMIC_RELAXED, __HIP_MEMORY_SCOPE_AGENT);
    }
    // hout write AFTER the flag: off the inter-block critical path
    if (tid < 128 && (tid & 16) == 0){
      u16* od = hout + ((size_t)b_g*SEQ + t_seq)*1536 + dir*HD + js*8 + jh_l;
      *(u32*)od = opair;
    }
  }
}

// ---------------------------------------------------------------------------
// logits[row][l] = tanh(h2)[row] . clf_w[l] + clf_b[l]  (th already tanh'd)
// ---------------------------------------------------------------------------
__global__ __launch_bounds__(256) void logits_kernel(const u16* __restrict__ th,
    const float* __restrict__ clf_w, const float* __restrict__ clf_b,
    float* __restrict__ logits)
{
  __shared__ u16 xl[8*1536];
  const int tid = threadIdx.x;
  const int row0 = blockIdx.x * 8;
  {
    const uint4* src = (const uint4*)(th + (size_t)row0*1536);
    uint4* dst = (uint4*)xl;
    #pragma unroll
    for (int i = 0; i < 6; i++) dst[i*256 + tid] = src[i*256 + tid];
  }
  __syncthreads();
  const int r = tid >> 5, l = tid & 31;
  if (l < NL){
    float acc = clf_b[l];
    const float* wr = clf_w + (size_t)l*1536;
    #pragma unroll 2
    for (int kk = 0; kk < 192; kk++){
      uint4 xv = *(const uint4*)&xl[r*1536 + kk*8];
      float4 w0 = *(const float4*)(wr + kk*8);
      float4 w1 = *(const float4*)(wr + kk*8 + 4);
      acc = fmaf(asf(xv.x<<16), w0.x, acc); acc = fmaf(asf(xv.x&0xffff0000u), w0.y, acc);
      acc = fmaf(asf(xv.y<<16), w0.z, acc); acc = fmaf(asf(xv.y&0xffff0000u), w0.w, acc);
      acc = fmaf(asf(xv.z<<16), w1.x, acc); acc = fmaf(asf(xv.z&0xffff0000u), w1.y, acc);
      acc = fmaf(asf(xv.w<<16), w1.z, acc); acc = fmaf(asf(xv.w&0xffff0000u), w1.w, acc);
    }
    logits[(size_t)(row0 + r)*NL + l] = acc;
  }
}

// ---------------------------------------------------------------------------
// CRF numerator + lengths (per b)
// ---------------------------------------------------------------------------
__global__ __launch_bounds__(256) void crf_num(const float* __restrict__ logits,
    const int* __restrict__ targets, const float* __restrict__ trans,
    const float* __restrict__ start, const float* __restrict__ endv,
    float* __restrict__ numlen)
{
  const int b = blockIdx.x;
  const int* tg = targets + (size_t)b*SEQ;
  float s = 0.f; int cnt = 0;
  for (int t = threadIdx.x; t < SEQ; t += 256){
    int cur = tg[t];
    if (cur >= 0){
      cnt++;
      float e = logits[((size_t)b*SEQ + t)*NL + cur];
      s += e;
      if (t > 0) s += trans[tg[t-1]*NL + cur];
    }
  }
  __shared__ float ss[256]; __shared__ int sc[256];
  ss[threadIdx.x] = s; sc[threadIdx.x] = cnt;
  __syncthreads();
  for (int o = 128; o > 0; o >>= 1){
    if (threadIdx.x < o){ ss[threadIdx.x] += ss[threadIdx.x+o]; sc[threadIdx.x] += sc[threadIdx.x+o]; }
    __syncthreads();
  }
  if (threadIdx.x == 0){
    int len = sc[0];
    numlen[b]      = ss[0] + start[tg[0]] + endv[tg[len-1]];
    numlen[16 + b] = (float)len;
  }
}

// ---------------------------------------------------------------------------
// CRF forward (denominator), one wave per b; logits staged in LDS once.
// ---------------------------------------------------------------------------
__global__ __launch_bounds__(64) void crf_fwd(const float* __restrict__ logits,
    const int* __restrict__ targets, const float* __restrict__ trans,
    const float* __restrict__ start, const float* __restrict__ endv,
    float* __restrict__ denom)
{
  const int b = blockIdx.x, lane = threadIdx.x;
  __shared__ float el[SEQ*NL];   // 51.2 KB
  __shared__ float tr[NL*NL];
  for (int i = lane; i < NL*NL; i += 64) tr[i] = trans[i];
  {
    const float4* src = (const float4*)(logits + (size_t)b*SEQ*NL);
    float4* dst = (float4*)el;
    for (int i = lane; i < SEQ*NL/4; i += 64) dst[i] = src[i];
  }
  __syncthreads();
  const bool act = lane < NL;
  const int j = act ? lane : 0;
  float alpha = act ? (start[j] + el[j]) : -3e38f;
  const int* tg = targets + (size_t)b*SEQ;
  for (int t = 1; t < SEQ; t++){
    if (tg[t] < 0) break;
    float e = el[t*NL + j];
    float v[NL]; float mx = -3e38f;
    #pragma unroll
    for (int i = 0; i < NL; i++){
      float ai = __shfl(alpha, i);
      v[i] = ai + tr[i*NL + j];
      mx = fmaxf(mx, v[i]);
    }
    float sum = 0.f;
    #pragma unroll
    for (int i = 0; i < NL; i++) sum += __expf(v[i] - mx);
    float nxt = mx + __logf(sum) + e;
    if (act) alpha = nxt;
  }
  float x = act ? alpha + endv[j] : -3e38f;
  float m2 = x;
  #pragma unroll
  for (int off = 32; off >= 1; off >>= 1) m2 = fmaxf(m2, __shfl_xor(m2, off));
  float se = __expf(x - m2);
  #pragma unroll
  for (int off = 32; off >= 1; off >>= 1) se += __shfl_xor(se, off);
  if (lane == 0) denom[b] = m2 + __logf(se);
}

__global__ void crf_final(const float* __restrict__ numlen, const float* __restrict__ denom,
                          float* __restrict__ out)
{
  if (blockIdx.x == 0 && threadIdx.x == 0){
    float sn = 0.f, sl = 0.f;
    for (int b = 0; b < 16; b++){ sn += numlen[b] - denom[b]; sl += numlen[16+b]; }
    out[0] = -sn / sl;
  }
}

// ---------------------------------------------------------------------------
extern "C" void kernel_launch(void* const* d_in, const int* in_sizes, int n_in,
                              void* d_out, int out_size, void* d_ws, size_t ws_size,
                              hipStream_t stream)
{
  const float* hidden  = (const float*)d_in[0];
  const int*   targets = (const int*)  d_in[1];
  const float* w_ih[4] = {(const float*)d_in[2], (const float*)d_in[6], (const float*)d_in[10], (const float*)d_in[14]};
  const float* w_hh[4] = {(const float*)d_in[3], (const float*)d_in[7], (const float*)d_in[11], (const float*)d_in[15]};
  const float* b_ih[4] = {(const float*)d_in[4], (const float*)d_in[8], (const float*)d_in[12], (const float*)d_in[16]};
  const float* b_hh[4] = {(const float*)d_in[5], (const float*)d_in[9], (const float*)d_in[13], (const float*)d_in[17]};
  const float* clf_w = (const float*)d_in[18];
  const float* clf_b = (const float*)d_in[19];
  const float* trans = (const float*)d_in[20];
  const float* start = (const float*)d_in[21];
  const float* endv  = (const float*)d_in[22];

  // workspace layout (~146 MB)
  char* p = (char*)d_ws;
  auto alloc = [&](size_t bytes){ void* r = (void*)p; p += (bytes + 255) & ~(size_t)255; return r; };
  float* bias   = (float*)alloc((size_t)4*G4*4);
  u16*   xgp    = (u16*)  alloc((size_t)2*XGD*2);             // 100.7 MB repacked
  u16*   h1     = (u16*)  alloc((size_t)B*SEQ*2*HD*2);        // 25.2 MB (doubles as th)
  u16*   hgbu   = (u16*)  alloc((size_t)2*2*16*768*2);        // 96 KB h ping-pong [ping][dir][b][k]
  u32*   flags  = (u32*)  alloc((size_t)2*NBLK*4);            // per-block flags
  float* logits = (float*)alloc((size_t)B*SEQ*NL*4);
  float* numlen = (float*)alloc(32*4);
  float* denom  = (float*)alloc(16*4);
  u16*   wb     = (u16*)  alloc((size_t)2*3072*1536*2);       // 18.9 MB bf16 W scratch
  if ((size_t)(p - (char*)d_ws) > ws_size) return;

  BPtrs bp;
  for (int i = 0; i < 4; i++){ bp.bi[i] = b_ih[i]; bp.bh[i] = b_hh[i]; }
  prep_bias<<<48, 256, 0, stream>>>(bp, bias);

  const dim3 ggrid(24, 64);
  const size_t hgb_bytes = (size_t)2*2*16*768*2;
  const size_t flg_bytes = (size_t)2*NBLK*4;
  const size_t w0 = (size_t)3072*768;    // u16 elems per l0 dir weight
  const size_t w1 = (size_t)3072*1536;

  // ---- layer 0 ----
  conv_bf16<<<512, 256, 0, stream>>>(w_ih[0], wb,      (int)(w0/8));
  conv_bf16<<<512, 256, 0, stream>>>(w_ih[1], wb + w0, (int)(w0/8));
  gemm_xg_mfma<float><<<ggrid, 256, 0, stream>>>(hidden, HD, wb,      bias + 0*G4, xgp);
  gemm_xg_mfma<float><<<ggrid, 256, 0, stream>>>(hidden, HD, wb + w0, bias + 1*G4, xgp + XGD);
  hipMemsetAsync(hgbu, 0, hgb_bytes, stream);
  hipMemsetAsync(flags, 0, flg_bytes, stream);
  {
    const u16* a0 = xgp; const float* a1 = w_hh[0]; const float* a2 = w_hh[1];
    u16* a3 = hgbu; u32* a4 = flags; u16* a5 = h1;
    void* args[] = { &a0, &a1, &a2, &a3, &a4, &a5 };
    hipLaunchCooperativeKernel(reinterpret_cast<void*>(&scan_kernel<0>),
                               dim3(2*NBLK), dim3(256), args, 0, stream);
  }

  // ---- layer 1 ----
  conv_bf16<<<512, 256, 0, stream>>>(w_ih[2], wb,      (int)(w1/8));
  conv_bf16<<<512, 256, 0, stream>>>(w_ih[3], wb + w1, (int)(w1/8));
  gemm_xg_mfma<u16><<<ggrid, 256, 0, stream>>>(h1, 2*HD, wb,      bias + 2*G4, xgp);
  gemm_xg_mfma<u16><<<ggrid, 256, 0, stream>>>(h1, 2*HD, wb + w1, bias + 3*G4, xgp + XGD);
  hipMemsetAsync(hgbu, 0, hgb_bytes, stream);
  hipMemsetAsync(flags, 0, flg_bytes, stream);
  {
    const u16* a0 = xgp; const float* a1 = w_hh[2]; const float* a2 = w_hh[3];
    u16* a3 = hgbu; u32* a4 = flags; u16* a5 = h1;
    void* args[] = { &a0, &a1, &a2, &a3, &a4, &a5 };
    hipLaunchCooperativeKernel(reinterpret_cast<void*>(&scan_kernel<1>),
                               dim3(2*NBLK), dim3(256), args, 0, stream);
  }

  // ---- classifier + CRF ----
  logits_kernel<<<1024, 256, 0, stream>>>(h1, clf_w, clf_b, logits);
  crf_num<<<16, 256, 0, stream>>>(logits, targets, trans, start, endv, numlen);
  crf_fwd<<<16, 64, 0, stream>>>(logits, targets, trans, start, endv, denom);
  crf_final<<<1, 64, 0, stream>>>(numlen, denom, (float*)d_out);
}